// Round 1
// baseline (809.946 us; speedup 1.0000x reference)
//
#include <hip/hip_runtime.h>
#include <math.h>

#define TT 9
#define HH 128
#define WW 128
#define BB 8
#define SLICE (HH*WW)           // 16384
#define CHW (TT*SLICE)          // 147456
#define BCH (2*CHW)             // 294912
#define TOT (BB*BCH)            // 2359296
#define INV_M (1.0f/147456.0f)

// ---------------- K1: per-batch max of t (b is sorted; contiguous chunks) ---
__global__ void k_tmax(const float* __restrict__ t, const int* __restrict__ b,
                       unsigned* __restrict__ gmax, int n, int chunk) {
    __shared__ unsigned sm[8];
    int tid = threadIdx.x;
    if (tid < 8) sm[tid] = 0u;
    __syncthreads();
    long base = (long)blockIdx.x * chunk;
    int curb = -1; unsigned curm = 0u;
    for (int j = tid; j < chunk; j += 256) {
        long i = base + j;
        if (i >= n) break;
        int bi = b[i];
        unsigned tv = __float_as_uint(t[i]);   // t >= 0 -> uint order == float order
        if (bi != curb) {
            if (curb >= 0) atomicMax(&sm[curb], curm);
            curb = bi; curm = tv;
        } else if (tv > curm) curm = tv;
    }
    if (curb >= 0) atomicMax(&sm[curb], curm);
    __syncthreads();
    if (tid < 8) { unsigned v = sm[tid]; if (v) atomicMax(&gmax[tid], v); }
}

// ---------------- K2: voxelize scatter ------------------------------------
__global__ void k_vox(const float* __restrict__ t, const int* __restrict__ x,
                      const int* __restrict__ y, const int* __restrict__ p,
                      const int* __restrict__ b, const unsigned* __restrict__ gmax,
                      float* __restrict__ vox, int n) {
    int i = blockIdx.x * blockDim.x + threadIdx.x;
    int stride = gridDim.x * blockDim.x;
    for (; i < n; i += stride) {
        int bi = b[i];
        float tmax = __uint_as_float(gmax[bi]);
        float ts = t[i] / tmax * 9.0f;          // same op order as reference
        int base = x[i] + WW * y[i] + CHW * p[i] + BCH * bi;
        float fl = floorf(ts);
        int i0 = (int)fl;
        if (i0 >= 0 && i0 < TT) {
            float v0 = 1.0f - (ts - fl);        // == ref: 1 - |ts - i0|
            atomicAdd(&vox[base + SLICE * i0], v0);
        }
        int i1 = i0 + 1;
        if (i1 >= 0 && i1 < TT) {
            float v1 = 1.0f - ((float)i1 - ts); // == ref: 1 - |ts - i1| (bit-exact)
            atomicAdd(&vox[base + SLICE * i1], v1);
        }
    }
}

// ---------------- K3: per-(b,c) sum / sumsq of vox -------------------------
__global__ void k_stats1(const float* __restrict__ vox, float* __restrict__ s1) {
    __shared__ float ss[256], sq[256];
    int bc = blockIdx.x >> 5, part = blockIdx.x & 31;
    const float4* vp = (const float4*)(vox + (long)bc * CHW);
    const int per = (CHW / 4) / 32;   // 1152 float4 per part
    float s = 0.f, q = 0.f;
    for (int j = part * per + threadIdx.x; j < (part + 1) * per; j += 256) {
        float4 v = vp[j];
        s += v.x + v.y + v.z + v.w;
        q += v.x * v.x + v.y * v.y + v.z * v.z + v.w * v.w;
    }
    ss[threadIdx.x] = s; sq[threadIdx.x] = q;
    __syncthreads();
    for (int ofs = 128; ofs > 0; ofs >>= 1) {
        if (threadIdx.x < ofs) { ss[threadIdx.x] += ss[threadIdx.x + ofs]; sq[threadIdx.x] += sq[threadIdx.x + ofs]; }
        __syncthreads();
    }
    if (threadIdx.x == 0) { atomicAdd(&s1[bc], ss[0]); atomicAdd(&s1[16 + bc], sq[0]); }
}

// ---------------- K4: time-corr mask (one block per (b,c,t) slice) ---------
__global__ void k_mask(const float* __restrict__ vox, float* __restrict__ mask) {
    __shared__ unsigned char sbx[SLICE];
    __shared__ unsigned char sar[SLICE];
    int bid = blockIdx.x;                 // 144 = 8*2*9
    int t = bid % 9, c = (bid / 9) & 1, bb = bid / 18;
    long off = (long)bb * BCH + (long)c * CHW;
    const float* vt = vox + off + (long)t * SLICE;
    int tn = (t + 1 < 9) ? t + 1 : 8;     // replication pad in T
    const float* vn = vox + off + (long)tn * SLICE;
    for (int i = threadIdx.x; i < SLICE; i += 256)
        sbx[i] = (vt[i] > 0.0f) ? 1 : 0;
    __syncthreads();
    for (int i = threadIdx.x; i < SLICE; i += 256) {
        int yy = i >> 7, xx = i & 127;
        int s = 0;
        for (int dy = -1; dy <= 1; ++dy) {
            int y2 = yy + dy; if ((unsigned)y2 >= 128u) continue;
            for (int dx = -1; dx <= 1; ++dx) {
                int x2 = xx + dx; if ((unsigned)x2 >= 128u) continue;
                s += sbx[(y2 << 7) + x2];
            }
        }
        // prev*bxn > 4/9  <=>  bxn==1 && boxsum >= 5   (exact, s is an integer)
        sar[i] = (vn[i] > 0.0f && s >= 5) ? 1 : 0;
    }
    __syncthreads();
    float* mt = mask + off + (long)t * SLICE;
    for (int i = threadIdx.x; i < SLICE; i += 256) {
        int yy = i >> 7, xx = i & 127;
        int s = 0;
        for (int dy = -1; dy <= 1; ++dy) {
            int y2 = yy + dy; if ((unsigned)y2 >= 128u) continue;
            for (int dx = -1; dx <= 1; ++dx) {
                int x2 = xx + dx; if ((unsigned)x2 >= 128u) continue;
                s += sar[(y2 << 7) + x2];
            }
        }
        mt[i] = (float)s / 9.0f;
    }
}

// ---------------- K5: fold stats + collapse conv1/dyn/conv3 to K[2][2][3] --
__global__ void k_prep(const float* __restrict__ conv1_w, const float* __restrict__ dyn_w,
                       const float* __restrict__ conv3_w, const float* __restrict__ s1,
                       float* __restrict__ nrm, float* __restrict__ Kc) {
    int tid = threadIdx.x;
    if (tid < 16) {
        float m = s1[tid] * INV_M;
        float var = s1[16 + tid] * INV_M - m * m;
        float inv = rsqrtf(var + 1e-5f);
        nrm[tid] = inv;           // scale
        nrm[16 + tid] = -m * inv; // shift
    }
    if (tid < 12) {
        int d = tid % 3, c = (tid / 3) & 1, o2 = tid / 6;
        float acc = 0.0f;
        for (int o = 0; o < 16; ++o) {
            float c3 = conv3_w[o2 * 16 + o];
            for (int i = 0; i < 16; ++i) {
                float wsum = 0.0f;
                for (int k = 0; k < 4; ++k) wsum += dyn_w[((k * 16 + o) * 16 + i) * 3 + d];
                acc += c3 * (0.25f * wsum) * conv1_w[i * 2 + c];
                // attention is exactly uniform: pooled mean of inorm output is 0
            }
        }
        Kc[tid] = acc;            // Kc[o2*6 + c*3 + d]
    }
}

// ---------------- K6: pre-act conv + sigmoid*mask + stats2 -----------------
__global__ void k_g(const float* __restrict__ vox, float* __restrict__ gm,
                    const float* __restrict__ nrm, const float* __restrict__ Kc,
                    float* __restrict__ s2) {
    int i = blockIdx.x * 256 + threadIdx.x;     // grid covers TOT exactly
    int bb = i / BCH;
    int o2 = (i / CHW) & 1;
    int t = (i / SLICE) % 9;
    int hw = i & (SLICE - 1);
    const float* Kk = Kc + o2 * 6;
    float pre = 0.0f;
    for (int c = 0; c < 2; ++c) {
        float sc = nrm[bb * 2 + c], sh = nrm[16 + bb * 2 + c];
        const float* vbase = vox + (long)bb * BCH + (long)c * CHW + hw;
        for (int d = 0; d < 3; ++d) {
            int tau = t - 1 + d;
            if ((unsigned)tau < 9u) {
                float nv = vbase[(long)tau * SLICE] * sc + sh;
                pre += Kk[c * 3 + d] * nv;
            }
        }
    }
    float sig = 1.0f / (1.0f + expf(-pre));
    float g = sig * gm[i];                      // gm holds mask, becomes g
    gm[i] = g;
    __shared__ float ss[256], sq[256];
    ss[threadIdx.x] = g; sq[threadIdx.x] = g * g;
    __syncthreads();
    for (int ofs = 128; ofs > 0; ofs >>= 1) {
        if (threadIdx.x < ofs) { ss[threadIdx.x] += ss[threadIdx.x + ofs]; sq[threadIdx.x] += sq[threadIdx.x + ofs]; }
        __syncthreads();
    }
    if (threadIdx.x == 0) {
        int bc = bb * 2 + o2;
        atomicAdd(&s2[bc], ss[0]); atomicAdd(&s2[16 + bc], sq[0]);
    }
}

// ---------------- K7: final instance norm in place -------------------------
__global__ void k_norm(float* __restrict__ out, const float* __restrict__ s2) {
    int i = blockIdx.x * 256 + threadIdx.x;
    int bc = i / CHW;
    float m = s2[bc] * INV_M;
    float var = s2[16 + bc] * INV_M - m * m;
    float inv = rsqrtf(var + 1e-5f);
    out[i] = (out[i] - m) * inv;
}

extern "C" void kernel_launch(void* const* d_in, const int* in_sizes, int n_in,
                              void* d_out, int out_size, void* d_ws, size_t ws_size,
                              hipStream_t stream) {
    const float* t  = (const float*)d_in[0];
    const int*   x  = (const int*)d_in[1];
    const int*   y  = (const int*)d_in[2];
    const int*   p  = (const int*)d_in[3];
    const int*   b  = (const int*)d_in[4];
    const float* conv1_w = (const float*)d_in[5];
    // d_in[6], d_in[7] (fc1_w, fc2_w): unused — attention is exactly uniform
    const float* dyn_w   = (const float*)d_in[8];
    const float* conv3_w = (const float*)d_in[9];
    float* out = (float*)d_out;
    int n = in_sizes[0];

    float*    ws   = (float*)d_ws;
    float*    vox  = ws;                         // TOT floats
    unsigned* gmax = (unsigned*)(ws + TOT);      // 8
    float*    s1   = ws + TOT + 8;               // 32
    float*    nrm  = ws + TOT + 40;              // 32
    float*    Kc   = ws + TOT + 72;              // 12
    float*    s2   = ws + TOT + 84;              // 32

    hipMemsetAsync(d_ws, 0, (size_t)(TOT + 128) * sizeof(float), stream);

    int chunk = (n + 2047) / 2048;
    k_tmax<<<2048, 256, 0, stream>>>(t, b, gmax, n, chunk);
    k_vox<<<4096, 256, 0, stream>>>(t, x, y, p, b, gmax, vox, n);
    k_stats1<<<512, 256, 0, stream>>>(vox, s1);
    k_mask<<<144, 256, 0, stream>>>(vox, out);   // d_out holds mask temporarily
    k_prep<<<1, 64, 0, stream>>>(conv1_w, dyn_w, conv3_w, s1, nrm, Kc);
    k_g<<<TOT / 256, 256, 0, stream>>>(vox, out, nrm, Kc, s2);
    k_norm<<<TOT / 256, 256, 0, stream>>>(out, s2);
}